// Round 1
// baseline (165.222 us; speedup 1.0000x reference)
//
#include <hip/hip_runtime.h>
#include <hip/hip_bf16.h>
#include <stdint.h>

// B=8192 triplet loss with hard-negative mining.
// prep: normalize -> bf16 + row sums
// dist_topk: bf16 MFMA 8192x8192 distances + per-row top-5 (16-way col split)
// merge_loss: merge splits, JAX threefry RNG, exact fp32 loss per row
// finalize: deterministic mean

#define NB 8192
#define ND 256
#define NSPLIT 16
#define CPS (NB / NSPLIT) // 512 cols per split
#define EPSF 1e-6f

// RNG mode: 0 = threefry partitionable, word = x^y (JAX >= 0.4.36 default)
//           1 = partitionable, word = x ; 2 = partitionable, word = y
//           3 = original (non-partitionable) threefry mode
#define RNG_MODE 0

typedef float f32x4 __attribute__((ext_vector_type(4)));
typedef short short8 __attribute__((ext_vector_type(8)));

struct Cand { float v; int i; };
struct U2 { uint32_t x, y; };

__host__ __device__ __forceinline__ uint32_t rotl32(uint32_t v, int n) {
  return (v << n) | (v >> (32 - n));
}

__host__ __device__ __forceinline__ U2 tf2x32(uint32_t k0, uint32_t k1,
                                              uint32_t x0, uint32_t x1) {
  uint32_t k2 = k0 ^ k1 ^ 0x1BD11BDAu;
#define TF_R(r) { x0 += x1; x1 = rotl32(x1, r); x1 ^= x0; }
  x0 += k0; x1 += k1;
  TF_R(13) TF_R(15) TF_R(26) TF_R(6)
  x0 += k1; x1 += k2 + 1u;
  TF_R(17) TF_R(29) TF_R(16) TF_R(24)
  x0 += k2; x1 += k0 + 2u;
  TF_R(13) TF_R(15) TF_R(26) TF_R(6)
  x0 += k0; x1 += k1 + 3u;
  TF_R(17) TF_R(29) TF_R(16) TF_R(24)
  x0 += k1; x1 += k2 + 4u;
  TF_R(13) TF_R(15) TF_R(26) TF_R(6)
  x0 += k2; x1 += k0 + 5u;
#undef TF_R
  U2 r; r.x = x0; r.y = x1; return r;
}

__device__ __forceinline__ uint32_t rng_word(U2 r) {
#if RNG_MODE == 1
  return r.x;
#elif RNG_MODE == 2
  return r.y;
#else
  return r.x ^ r.y;
#endif
}

__device__ __forceinline__ uint32_t coin_word(uint32_t ka, uint32_t kb, int i) {
#if RNG_MODE == 3
  if (i < NB / 2) return tf2x32(ka, kb, (uint32_t)i, (uint32_t)(i + NB / 2)).x;
  else            return tf2x32(ka, kb, (uint32_t)(i - NB / 2), (uint32_t)i).y;
#else
  return rng_word(tf2x32(ka, kb, 0u, (uint32_t)i));
#endif
}

__device__ __forceinline__ void rank_words(uint32_t ka, uint32_t kb, int i,
                                           uint32_t& hb, uint32_t& lb) {
#if RNG_MODE == 3
  U2 r = tf2x32(ka, kb, (uint32_t)i, (uint32_t)(i + NB));
  hb = r.x; lb = r.y;
#else
  hb = rng_word(tf2x32(ka, kb, 0u, (uint32_t)i));
  lb = rng_word(tf2x32(ka, kb, 0u, (uint32_t)(NB + i)));
#endif
}

// ---------------- prep: normalize, bf16, row sums ----------------
__global__ __launch_bounds__(256) void prep_kernel(
    const float* __restrict__ x,
    __hip_bfloat16* __restrict__ abf, __hip_bfloat16* __restrict__ pbf,
    float* __restrict__ ra, float* __restrict__ rp) {
  const int i = blockIdx.x;
  const int t = threadIdx.x;
  const int w = t >> 6;
  __shared__ float lred[8];

  float xa = x[(size_t)i * 512 + t];
  float xp = x[(size_t)i * 512 + 256 + t];

  float s0 = xa * xa, s1 = xp * xp;
#pragma unroll
  for (int off = 32; off; off >>= 1) { s0 += __shfl_xor(s0, off); s1 += __shfl_xor(s1, off); }
  if ((t & 63) == 0) { lred[w * 2] = s0; lred[w * 2 + 1] = s1; }
  __syncthreads();
  float sa = lred[0] + lred[2] + lred[4] + lred[6];
  float sp = lred[1] + lred[3] + lred[5] + lred[7];
  float na = fmaxf(sqrtf(sa), 1e-12f);
  float np = fmaxf(sqrtf(sp), 1e-12f);
  float ad = xa / na, pd = xp / np;
  abf[(size_t)i * 256 + t] = __float2bfloat16(ad);
  pbf[(size_t)i * 256 + t] = __float2bfloat16(pd);

  float r0 = ad, r1 = pd;
#pragma unroll
  for (int off = 32; off; off >>= 1) { r0 += __shfl_xor(r0, off); r1 += __shfl_xor(r1, off); }
  __syncthreads();
  if ((t & 63) == 0) { lred[w * 2] = r0; lred[w * 2 + 1] = r1; }
  __syncthreads();
  if (t == 0) {
    ra[i] = lred[0] + lred[2] + lred[4] + lred[6];
    rp[i] = lred[1] + lred[3] + lred[5] + lred[7];
  }
}

// ---------------- dist + per-row top-5 ----------------
// grid: (64 row-blocks of 128 rows, 16 col-splits of 512 cols), 256 thr = 4 waves
__global__ __launch_bounds__(256, 3) void dist_topk_kernel(
    const __hip_bfloat16* __restrict__ abf, const __hip_bfloat16* __restrict__ pbf,
    const float* __restrict__ ra, const float* __restrict__ rp,
    Cand* __restrict__ part) {
  __shared__ uint4 tile4[1024];          // 16 KB swizzled B tile (32 cols x 256 k bf16)
  __shared__ float rpTile[32];
  __shared__ float dump[4][32][37];      // per-wave d2 tile, pad 37 -> conflict-free scan
  char* tile = (char*)tile4;

  const int tid = threadIdx.x;
  const int w = tid >> 6, l = tid & 63;
  const int lo = l & 15, hi = l >> 4;
  const int rb = blockIdx.x, sp = blockIdx.y;
  const int wrow = rb * 128 + w * 32;

  // A fragments for this wave's 32 rows, all K, kept in registers.
  short8 aF[2][8];
#pragma unroll
  for (int mi = 0; mi < 2; ++mi)
#pragma unroll
    for (int kk = 0; kk < 8; ++kk) {
      const int row = wrow + mi * 16 + lo;
      const uint4* src = (const uint4*)((const char*)abf + ((size_t)row * 256 + kk * 32 + hi * 8) * 2);
      uint4 v = *src;
      aF[mi][kk] = __builtin_bit_cast(short8, v);
    }

  float rowc[8];
#pragma unroll
  for (int mi = 0; mi < 2; ++mi)
#pragma unroll
    for (int r = 0; r < 4; ++r)
      rowc[mi * 4 + r] = 2.0f + (float)ND * EPSF * EPSF +
                         2.0f * EPSF * ra[wrow + mi * 16 + hi * 4 + r];

  const float INF = __builtin_inff();
  float tv0 = INF, tv1 = INF, tv2 = INF, tv3 = INF, tv4 = INF;
  int ti0 = 0, ti1 = 0, ti2 = 0, ti3 = 0, ti4 = 0;

  for (int it = 0; it < CPS / 32; ++it) {
    const int c0 = sp * CPS + it * 32;
    // stage B tile: 16 KB, 64 B per thread, XOR-swizzle bits 4..6 by (col&7)
#pragma unroll
    for (int j = 0; j < 4; ++j) {
      const int off = (tid * 4 + j) * 16;
      const int cc = off >> 9;
      const int kb = off & 511;
      uint4 v = *(const uint4*)((const char*)pbf + ((size_t)(c0 + cc) * 512 + kb));
      *(uint4*)(tile + (off ^ ((cc & 7) << 4))) = v;
    }
    if (tid < 32) rpTile[tid] = rp[c0 + tid];
    __syncthreads();

    f32x4 acc[2][2];
#pragma unroll
    for (int mi = 0; mi < 2; ++mi)
#pragma unroll
      for (int ni = 0; ni < 2; ++ni) { f32x4 z = {0.f, 0.f, 0.f, 0.f}; acc[mi][ni] = z; }

#pragma unroll
    for (int kk = 0; kk < 8; ++kk) {
      short8 bF0, bF1;
      {
        const int cc = lo;
        const int lin = cc * 512 + kk * 64 + hi * 16;
        bF0 = *(const short8*)(tile + (lin ^ ((cc & 7) << 4)));
      }
      {
        const int cc = 16 + lo;
        const int lin = cc * 512 + kk * 64 + hi * 16;
        bF1 = *(const short8*)(tile + (lin ^ ((cc & 7) << 4)));
      }
      acc[0][0] = __builtin_amdgcn_mfma_f32_16x16x32_bf16(aF[0][kk], bF0, acc[0][0], 0, 0, 0);
      acc[0][1] = __builtin_amdgcn_mfma_f32_16x16x32_bf16(aF[0][kk], bF1, acc[0][1], 0, 0, 0);
      acc[1][0] = __builtin_amdgcn_mfma_f32_16x16x32_bf16(aF[1][kk], bF0, acc[1][0], 0, 0, 0);
      acc[1][1] = __builtin_amdgcn_mfma_f32_16x16x32_bf16(aF[1][kk], bF1, acc[1][1], 0, 0, 0);
    }

    // epilogue: ip -> d2, dump to LDS (C/D layout: col=lane&15, row=(lane>>4)*4+reg)
#pragma unroll
    for (int mi = 0; mi < 2; ++mi)
#pragma unroll
      for (int ni = 0; ni < 2; ++ni)
#pragma unroll
        for (int r = 0; r < 4; ++r) {
          const int rt = mi * 16 + hi * 4 + r;
          const int ct = ni * 16 + lo;
          float d2 = rowc[mi * 4 + r] - 2.0f * acc[mi][ni][r] - 2.0f * EPSF * rpTile[ct];
          if (wrow + rt == c0 + ct) d2 = INF;
          dump[w][rt][ct] = d2;
        }
    asm volatile("s_waitcnt lgkmcnt(0)" ::: "memory");
    __builtin_amdgcn_sched_barrier(0);

    if (l < 32) {
#pragma unroll 8
      for (int c = 0; c < 32; ++c) {
        const float v = dump[w][l][c];
        if (v < tv4) {
          const int ci = c0 + c;
          const bool b0 = v < tv0, b1 = v < tv1, b2 = v < tv2, b3 = v < tv3;
          tv4 = b3 ? tv3 : v;                 ti4 = b3 ? ti3 : ci;
          tv3 = b2 ? tv2 : (b3 ? v : tv3);    ti3 = b2 ? ti2 : (b3 ? ci : ti3);
          tv2 = b1 ? tv1 : (b2 ? v : tv2);    ti2 = b1 ? ti1 : (b2 ? ci : ti2);
          tv1 = b0 ? tv0 : (b1 ? v : tv1);    ti1 = b0 ? ti0 : (b1 ? ci : ti1);
          tv0 = b0 ? v : tv0;                 ti0 = b0 ? ci : ti0;
        }
      }
    }
    __syncthreads();
  }

  if (l < 32) {
    const int row = wrow + l;
    Cand* dst = part + ((size_t)row * NSPLIT + sp) * 5;
    dst[0].v = tv0; dst[0].i = ti0;
    dst[1].v = tv1; dst[1].i = ti1;
    dst[2].v = tv2; dst[2].i = ti2;
    dst[3].v = tv3; dst[3].i = ti3;
    dst[4].v = tv4; dst[4].i = ti4;
  }
}

// ---------------- merge splits + RNG + exact fp32 loss ----------------
__global__ __launch_bounds__(64) void merge_loss_kernel(
    const float* __restrict__ x, const Cand* __restrict__ part,
    float* __restrict__ rowloss,
    uint32_t k1a, uint32_t k1b, uint32_t k2a, uint32_t k2b) {
  const int i = blockIdx.x, l = threadIdx.x;
  __shared__ Cand cs[80];
  const Cand* src = part + (size_t)i * (NSPLIT * 5);
  cs[l] = src[l];
  if (l < 16) cs[64 + l] = src[64 + l];
  __syncthreads();

  // merge: candidates arrive in (split asc, value asc, idx-tiebreak) order;
  // strict-< insertion preserves lax.top_k lower-index tie-break.
  const float INF = __builtin_inff();
  float tv0 = INF, tv1 = INF, tv2 = INF, tv3 = INF, tv4 = INF;
  int ti0 = 0, ti1 = 0, ti2 = 0, ti3 = 0, ti4 = 0;
  for (int k = 0; k < 80; ++k) {
    const float v = cs[k].v;
    if (v < tv4) {
      const int ci = cs[k].i;
      const bool b0 = v < tv0, b1 = v < tv1, b2 = v < tv2, b3 = v < tv3;
      tv4 = b3 ? tv3 : v;                 ti4 = b3 ? ti3 : ci;
      tv3 = b2 ? tv2 : (b3 ? v : tv3);    ti3 = b2 ? ti2 : (b3 ? ci : ti3);
      tv2 = b1 ? tv1 : (b2 ? v : tv2);    ti2 = b1 ? ti1 : (b2 ? ci : ti2);
      tv1 = b0 ? tv0 : (b1 ? v : tv1);    ti1 = b0 ? ti0 : (b1 ? ci : ti1);
      tv0 = b0 ? v : tv0;                 ti0 = b0 ? ci : ti0;
    }
  }

  // RNG (all lanes redundantly; uniform branches)
  const uint32_t cw = coin_word(k1a, k1b, i);
  const bool coin = (cw >> 31) == 0u;   // uniform < 0.5  <=>  MSB == 0
  uint32_t hb, lb;
  rank_words(k2a, k2b, i, hb, lb);
  const int rr = (int)(((hb % 5u) + (lb % 5u)) % 5u);
  const int rank = coin ? 0 : rr;
  const int neg = (rank == 0) ? ti0 : (rank == 1) ? ti1 : (rank == 2) ? ti2
                : (rank == 3) ? ti3 : ti4;

  // exact loss from raw x (renormalize: v / max(sqrt(sum v^2), 1e-12))
  const float4 xa = *(const float4*)(x + (size_t)i * 512 + l * 4);
  const float4 xp = *(const float4*)(x + (size_t)i * 512 + 256 + l * 4);
  const float4 xn = *(const float4*)(x + (size_t)neg * 512 + 256 + l * 4);
  float sa = xa.x * xa.x + xa.y * xa.y + xa.z * xa.z + xa.w * xa.w;
  float sp = xp.x * xp.x + xp.y * xp.y + xp.z * xp.z + xp.w * xp.w;
  float sn = xn.x * xn.x + xn.y * xn.y + xn.z * xn.z + xn.w * xn.w;
#pragma unroll
  for (int off = 32; off; off >>= 1) {
    sa += __shfl_xor(sa, off); sp += __shfl_xor(sp, off); sn += __shfl_xor(sn, off);
  }
  const float na = fmaxf(sqrtf(sa), 1e-12f);
  const float np = fmaxf(sqrtf(sp), 1e-12f);
  const float nn = fmaxf(sqrtf(sn), 1e-12f);

  float pos = 0.f, ng = 0.f;
  {
    float av, pv, nv, dp, dn;
    av = xa.x / na; pv = xp.x / np; nv = xn.x / nn;
    dp = av - pv + EPSF; pos += dp * dp; dn = av - nv + EPSF; ng += dn * dn;
    av = xa.y / na; pv = xp.y / np; nv = xn.y / nn;
    dp = av - pv + EPSF; pos += dp * dp; dn = av - nv + EPSF; ng += dn * dn;
    av = xa.z / na; pv = xp.z / np; nv = xn.z / nn;
    dp = av - pv + EPSF; pos += dp * dp; dn = av - nv + EPSF; ng += dn * dn;
    av = xa.w / na; pv = xp.w / np; nv = xn.w / nn;
    dp = av - pv + EPSF; pos += dp * dp; dn = av - nv + EPSF; ng += dn * dn;
  }
#pragma unroll
  for (int off = 32; off; off >>= 1) {
    pos += __shfl_xor(pos, off); ng += __shfl_xor(ng, off);
  }
  if (l == 0) rowloss[i] = fmaxf(pos - ng, 0.0f);
}

// ---------------- deterministic mean ----------------
__global__ __launch_bounds__(256) void finalize_kernel(
    const float* __restrict__ rowloss, float* __restrict__ out) {
  __shared__ float s[256];
  const int t = threadIdx.x;
  float a = 0.f;
  for (int k = 0; k < NB / 256; ++k) a += rowloss[t + 256 * k];
  s[t] = a;
  __syncthreads();
  for (int h = 128; h; h >>= 1) {
    if (t < h) s[t] += s[t + h];
    __syncthreads();
  }
  if (t == 0) out[0] = s[0] / (float)NB;
}

extern "C" void kernel_launch(void* const* d_in, const int* in_sizes, int n_in,
                              void* d_out, int out_size, void* d_ws, size_t ws_size,
                              hipStream_t stream) {
  (void)in_sizes; (void)n_in; (void)out_size; (void)ws_size;
  const float* x = (const float*)d_in[0];
  float* out = (float*)d_out;
  char* ws = (char*)d_ws;

  __hip_bfloat16* abf = (__hip_bfloat16*)(ws);                       // 4 MB
  __hip_bfloat16* pbf = (__hip_bfloat16*)(ws + (size_t)4 * 1024 * 1024);  // 4 MB
  float* ra = (float*)(ws + (size_t)8 * 1024 * 1024);                // 32 KB
  float* rp = (float*)(ws + (size_t)8 * 1024 * 1024 + 32 * 1024);    // 32 KB
  Cand* part = (Cand*)(ws + (size_t)8 * 1024 * 1024 + 64 * 1024);    // 5.24 MB
  float* rowloss = (float*)(ws + (size_t)8 * 1024 * 1024 + 64 * 1024 +
                            (size_t)NB * NSPLIT * 5 * sizeof(Cand)); // 32 KB

  // JAX: kr = key(1) -> [0,1]; k1, k2 = split(kr)
  uint32_t k1a, k1b, k2a, k2b;
#if RNG_MODE == 3
  {
    U2 c0 = tf2x32(0u, 1u, 0u, 2u);
    U2 c1 = tf2x32(0u, 1u, 1u, 3u);
    k1a = c0.x; k1b = c1.x;
    k2a = c0.y; k2b = c1.y;
  }
#else
  {
    U2 c0 = tf2x32(0u, 1u, 0u, 0u);
    U2 c1 = tf2x32(0u, 1u, 0u, 1u);
    k1a = c0.x; k1b = c0.y;
    k2a = c1.x; k2b = c1.y;
  }
#endif

  prep_kernel<<<NB, 256, 0, stream>>>(x, abf, pbf, ra, rp);
  dist_topk_kernel<<<dim3(NB / 128, NSPLIT), 256, 0, stream>>>(abf, pbf, ra, rp, part);
  merge_loss_kernel<<<NB, 64, 0, stream>>>(x, part, rowloss, k1a, k1b, k2a, k2b);
  finalize_kernel<<<1, 256, 0, stream>>>(rowloss, out);
}

// Round 2
// 125.760 us; speedup vs baseline: 1.3138x; 1.3138x over previous
//
#include <hip/hip_runtime.h>
#include <hip/hip_bf16.h>
#include <stdint.h>

// B=8192 triplet loss with hard-negative mining.
// prep: normalize -> bf16
// dist_topk: swapped-operand bf16 MFMA; per-lane in-register top-5 of ip
//            (row-constant terms don't affect per-row ordering; the per-col
//            2*eps*rp term (~6e-5) is below the bf16 ip noise already accepted)
// merge_loss: merge 16 splits (lex: ip desc, idx asc), JAX threefry RNG,
//             exact fp32 loss per row
// finalize: deterministic mean

#define NB 8192
#define ND 256
#define NSPLIT 16
#define CPS (NB / NSPLIT) // 512 cols per split
#define CPI 64            // cols per iteration
#define NIT (CPS / CPI)   // 8
#define EPSF 1e-6f

typedef float f32x4 __attribute__((ext_vector_type(4)));
typedef short short8 __attribute__((ext_vector_type(8)));

struct Cand { float v; int i; };
struct U2 { uint32_t x, y; };

__host__ __device__ __forceinline__ uint32_t rotl32(uint32_t v, int n) {
  return (v << n) | (v >> (32 - n));
}

__host__ __device__ __forceinline__ U2 tf2x32(uint32_t k0, uint32_t k1,
                                              uint32_t x0, uint32_t x1) {
  uint32_t k2 = k0 ^ k1 ^ 0x1BD11BDAu;
#define TF_R(r) { x0 += x1; x1 = rotl32(x1, r); x1 ^= x0; }
  x0 += k0; x1 += k1;
  TF_R(13) TF_R(15) TF_R(26) TF_R(6)
  x0 += k1; x1 += k2 + 1u;
  TF_R(17) TF_R(29) TF_R(16) TF_R(24)
  x0 += k2; x1 += k0 + 2u;
  TF_R(13) TF_R(15) TF_R(26) TF_R(6)
  x0 += k0; x1 += k1 + 3u;
  TF_R(17) TF_R(29) TF_R(16) TF_R(24)
  x0 += k1; x1 += k2 + 4u;
  TF_R(13) TF_R(15) TF_R(26) TF_R(6)
  x0 += k2; x1 += k0 + 5u;
#undef TF_R
  U2 r; r.x = x0; r.y = x1; return r;
}

__device__ __forceinline__ uint32_t rng_word(U2 r) { return r.x ^ r.y; }

__device__ __forceinline__ bool lex_gt(float v, int i, float tv, int ti) {
  return (v > tv) || (v == tv && i < ti);
}

// ---------------- prep: normalize -> bf16 ----------------
__global__ __launch_bounds__(256) void prep_kernel(
    const float* __restrict__ x,
    __hip_bfloat16* __restrict__ abf, __hip_bfloat16* __restrict__ pbf) {
  const int i = blockIdx.x;
  const int t = threadIdx.x;
  const int w = t >> 6;
  __shared__ float lred[8];

  float xa = x[(size_t)i * 512 + t];
  float xp = x[(size_t)i * 512 + 256 + t];

  float s0 = xa * xa, s1 = xp * xp;
#pragma unroll
  for (int off = 32; off; off >>= 1) { s0 += __shfl_xor(s0, off); s1 += __shfl_xor(s1, off); }
  if ((t & 63) == 0) { lred[w * 2] = s0; lred[w * 2 + 1] = s1; }
  __syncthreads();
  float sa = lred[0] + lred[2] + lred[4] + lred[6];
  float sp = lred[1] + lred[3] + lred[5] + lred[7];
  float na = fmaxf(sqrtf(sa), 1e-12f);
  float np = fmaxf(sqrtf(sp), 1e-12f);
  abf[(size_t)i * 256 + t] = __float2bfloat16(xa / na);
  pbf[(size_t)i * 256 + t] = __float2bfloat16(xp / np);
}

// ---------------- dist + per-row top-5 (in-register) ----------------
// grid: (64 row-blocks of 128 rows, 16 col-splits of 512 cols), 256 thr = 4 waves
// Swapped MFMA: acc = mfma(bF, aF): lane (lo,hi) holds, per (mi,ni):
//   a-row = wrow + mi*16 + lo (n index), p-cols = c0 + ni*16 + hi*4 + reg (m index)
__global__ __launch_bounds__(256) void dist_topk_kernel(
    const __hip_bfloat16* __restrict__ abf, const __hip_bfloat16* __restrict__ pbf,
    Cand* __restrict__ part) {
  __shared__ char tile[32768]; // 64 cols x 256 k bf16, XOR-swizzled; reused as merge scratch

  const int tid = threadIdx.x;
  const int w = tid >> 6, l = tid & 63;
  const int lo = l & 15, hi = l >> 4;
  const int rb = blockIdx.x, sp = blockIdx.y;
  const int wrow = rb * 128 + w * 32;

  // A fragments (B-operand position; layout: row = lo, k = hi*8+j), all K in regs.
  short8 aF[2][8];
#pragma unroll
  for (int mi = 0; mi < 2; ++mi)
#pragma unroll
    for (int kk = 0; kk < 8; ++kk) {
      const int row = wrow + mi * 16 + lo;
      aF[mi][kk] = __builtin_bit_cast(short8,
          *(const uint4*)((const char*)abf + (size_t)row * 512 + kk * 64 + hi * 16));
    }

  const float NINF = -__builtin_inff();
  const int rowA = wrow + lo, rowB = wrow + 16 + lo;
  float avA0 = NINF, avA1 = NINF, avA2 = NINF, avA3 = NINF, avA4 = NINF;
  int   aiA0 = 0, aiA1 = 0, aiA2 = 0, aiA3 = 0, aiA4 = 0;
  float avB0 = NINF, avB1 = NINF, avB2 = NINF, avB3 = NINF, avB4 = NINF;
  int   aiB0 = 0, aiB1 = 0, aiB2 = 0, aiB3 = 0, aiB4 = 0;

  for (int it = 0; it < NIT; ++it) {
    const int c0 = sp * CPS + it * CPI;
    // stage 32 KB: 128 B/thread, swizzle bits 4..6 of byte offset by (col&7)
#pragma unroll
    for (int j = 0; j < 8; ++j) {
      const int off = (tid * 8 + j) * 16;
      const int cc = off >> 9;
      const int kb = off & 511;
      uint4 v = *(const uint4*)((const char*)pbf + (size_t)(c0 + cc) * 512 + kb);
      *(uint4*)(tile + (off ^ ((cc & 7) << 4))) = v;
    }
    __syncthreads();

    f32x4 acc[2][4];
#pragma unroll
    for (int mi = 0; mi < 2; ++mi)
#pragma unroll
      for (int ni = 0; ni < 4; ++ni) { f32x4 z = {0.f, 0.f, 0.f, 0.f}; acc[mi][ni] = z; }

#pragma unroll
    for (int kk = 0; kk < 8; ++kk) {
      short8 bF[4];
#pragma unroll
      for (int ni = 0; ni < 4; ++ni) {
        const int cc = ni * 16 + lo;
        const int lin = cc * 512 + kk * 64 + hi * 16;
        bF[ni] = *(const short8*)(tile + (lin ^ ((cc & 7) << 4)));
      }
#pragma unroll
      for (int ni = 0; ni < 4; ++ni) {
        acc[0][ni] = __builtin_amdgcn_mfma_f32_16x16x32_bf16(bF[ni], aF[0][kk], acc[0][ni], 0, 0, 0);
        acc[1][ni] = __builtin_amdgcn_mfma_f32_16x16x32_bf16(bF[ni], aF[1][kk], acc[1][ni], 0, 0, 0);
      }
    }
    __syncthreads();

    // in-register mining: ci ascending per lane (it asc, ni asc, r asc)
#pragma unroll
    for (int ni = 0; ni < 4; ++ni)
#pragma unroll
      for (int r = 0; r < 4; ++r) {
        const int ci = c0 + ni * 16 + hi * 4 + r;
        float vA = acc[0][ni][r];
        if (ci == rowA) vA = NINF;
        if (vA > avA4) {
          const bool b0 = vA > avA0, b1 = vA > avA1, b2 = vA > avA2, b3 = vA > avA3;
          avA4 = b3 ? avA3 : vA;               aiA4 = b3 ? aiA3 : ci;
          avA3 = b2 ? avA2 : (b3 ? vA : avA3); aiA3 = b2 ? aiA2 : (b3 ? ci : aiA3);
          avA2 = b1 ? avA1 : (b2 ? vA : avA2); aiA2 = b1 ? aiA1 : (b2 ? ci : aiA2);
          avA1 = b0 ? avA0 : (b1 ? vA : avA1); aiA1 = b0 ? aiA0 : (b1 ? ci : aiA1);
          avA0 = b0 ? vA : avA0;               aiA0 = b0 ? ci : aiA0;
        }
        float vB = acc[1][ni][r];
        if (ci == rowB) vB = NINF;
        if (vB > avB4) {
          const bool b0 = vB > avB0, b1 = vB > avB1, b2 = vB > avB2, b3 = vB > avB3;
          avB4 = b3 ? avB3 : vB;               aiB4 = b3 ? aiB3 : ci;
          avB3 = b2 ? avB2 : (b3 ? vB : avB3); aiB3 = b2 ? aiB2 : (b3 ? ci : aiB3);
          avB2 = b1 ? avB1 : (b2 ? vB : avB2); aiB2 = b1 ? aiB1 : (b2 ? ci : aiB2);
          avB1 = b0 ? avB0 : (b1 ? vB : avB1); aiB1 = b0 ? aiB0 : (b1 ? ci : aiB1);
          avB0 = b0 ? vB : avB0;               aiB0 = b0 ? ci : aiB0;
        }
      }
  }

  // cross-hi merge via LDS scratch (each wave its own 5120 B region)
  __syncthreads(); // all tile reads done
  float2* sc = (float2*)tile;
  {
    const int base = w * 640 + (hi * 16 + lo) * 10;
#pragma unroll
    for (int k = 0; k < 5; ++k) {
      float2 e;
      e.x = (k == 0) ? avA0 : (k == 1) ? avA1 : (k == 2) ? avA2 : (k == 3) ? avA3 : avA4;
      e.y = __int_as_float((k == 0) ? aiA0 : (k == 1) ? aiA1 : (k == 2) ? aiA2 : (k == 3) ? aiA3 : aiA4);
      sc[base + k] = e;
    }
#pragma unroll
    for (int k = 0; k < 5; ++k) {
      float2 e;
      e.x = (k == 0) ? avB0 : (k == 1) ? avB1 : (k == 2) ? avB2 : (k == 3) ? avB3 : avB4;
      e.y = __int_as_float((k == 0) ? aiB0 : (k == 1) ? aiB1 : (k == 2) ? aiB2 : (k == 3) ? aiB3 : aiB4);
      sc[base + 5 + k] = e;
    }
  }
  __syncthreads();

  if (l < 32) {
    const int mi = l >> 4, lo2 = l & 15;
    float tv0 = NINF, tv1 = NINF, tv2 = NINF, tv3 = NINF, tv4 = NINF;
    int ti0 = 0, ti1 = 0, ti2 = 0, ti3 = 0, ti4 = 0;
#pragma unroll
    for (int h2 = 0; h2 < 4; ++h2)
#pragma unroll
      for (int k = 0; k < 5; ++k) {
        const float2 e = sc[w * 640 + (h2 * 16 + lo2) * 10 + mi * 5 + k];
        const float v = e.x;
        const int ci = __float_as_int(e.y);
        if (lex_gt(v, ci, tv4, ti4)) {
          const bool g0 = lex_gt(v, ci, tv0, ti0), g1 = lex_gt(v, ci, tv1, ti1),
                     g2 = lex_gt(v, ci, tv2, ti2), g3 = lex_gt(v, ci, tv3, ti3);
          tv4 = g3 ? tv3 : v;              ti4 = g3 ? ti3 : ci;
          tv3 = g2 ? tv2 : (g3 ? v : tv3); ti3 = g2 ? ti2 : (g3 ? ci : ti3);
          tv2 = g1 ? tv1 : (g2 ? v : tv2); ti2 = g1 ? ti1 : (g2 ? ci : ti2);
          tv1 = g0 ? tv0 : (g1 ? v : tv1); ti1 = g0 ? ti0 : (g1 ? ci : ti1);
          tv0 = g0 ? v : tv0;              ti0 = g0 ? ci : ti0;
        }
      }
    const int row = wrow + mi * 16 + lo2;
    Cand* dst = part + ((size_t)row * NSPLIT + sp) * 5;
    dst[0].v = tv0; dst[0].i = ti0;
    dst[1].v = tv1; dst[1].i = ti1;
    dst[2].v = tv2; dst[2].i = ti2;
    dst[3].v = tv3; dst[3].i = ti3;
    dst[4].v = tv4; dst[4].i = ti4;
  }
}

// ---------------- merge splits + RNG + exact fp32 loss ----------------
__global__ __launch_bounds__(64) void merge_loss_kernel(
    const float* __restrict__ x, const Cand* __restrict__ part,
    float* __restrict__ rowloss,
    uint32_t k1a, uint32_t k1b, uint32_t k2a, uint32_t k2b) {
  const int i = blockIdx.x, l = threadIdx.x;
  __shared__ Cand cs[80];
  const Cand* src = part + (size_t)i * (NSPLIT * 5);
  cs[l] = src[l];
  if (l < 16) cs[64 + l] = src[64 + l];
  __syncthreads();

  const float NINF = -__builtin_inff();
  float tv0 = NINF, tv1 = NINF, tv2 = NINF, tv3 = NINF, tv4 = NINF;
  int ti0 = 0, ti1 = 0, ti2 = 0, ti3 = 0, ti4 = 0;
  for (int k = 0; k < 80; ++k) {
    const float v = cs[k].v;
    const int ci = cs[k].i;
    if (lex_gt(v, ci, tv4, ti4)) {
      const bool g0 = lex_gt(v, ci, tv0, ti0), g1 = lex_gt(v, ci, tv1, ti1),
                 g2 = lex_gt(v, ci, tv2, ti2), g3 = lex_gt(v, ci, tv3, ti3);
      tv4 = g3 ? tv3 : v;              ti4 = g3 ? ti3 : ci;
      tv3 = g2 ? tv2 : (g3 ? v : tv3); ti3 = g2 ? ti2 : (g3 ? ci : ti3);
      tv2 = g1 ? tv1 : (g2 ? v : tv2); ti2 = g1 ? ti1 : (g2 ? ci : ti2);
      tv1 = g0 ? tv0 : (g1 ? v : tv1); ti1 = g0 ? ti0 : (g1 ? ci : ti1);
      tv0 = g0 ? v : tv0;              ti0 = g0 ? ci : ti0;
    }
  }

  // RNG: coin = uniform(k1) < 0.5 <=> MSB==0 ; randint(k2,0,5)
  const uint32_t cw = rng_word(tf2x32(k1a, k1b, 0u, (uint32_t)i));
  const bool coin = (cw >> 31) == 0u;
  const uint32_t hb = rng_word(tf2x32(k2a, k2b, 0u, (uint32_t)i));
  const uint32_t lb = rng_word(tf2x32(k2a, k2b, 0u, (uint32_t)(NB + i)));
  const int rr = (int)(((hb % 5u) + (lb % 5u)) % 5u);
  const int rank = coin ? 0 : rr;
  const int neg = (rank == 0) ? ti0 : (rank == 1) ? ti1 : (rank == 2) ? ti2
                : (rank == 3) ? ti3 : ti4;

  // exact fp32 loss from raw x
  const float4 xa = *(const float4*)(x + (size_t)i * 512 + l * 4);
  const float4 xp = *(const float4*)(x + (size_t)i * 512 + 256 + l * 4);
  const float4 xn = *(const float4*)(x + (size_t)neg * 512 + 256 + l * 4);
  float sa = xa.x * xa.x + xa.y * xa.y + xa.z * xa.z + xa.w * xa.w;
  float sp = xp.x * xp.x + xp.y * xp.y + xp.z * xp.z + xp.w * xp.w;
  float sn = xn.x * xn.x + xn.y * xn.y + xn.z * xn.z + xn.w * xn.w;
#pragma unroll
  for (int off = 32; off; off >>= 1) {
    sa += __shfl_xor(sa, off); sp += __shfl_xor(sp, off); sn += __shfl_xor(sn, off);
  }
  const float na = fmaxf(sqrtf(sa), 1e-12f);
  const float np = fmaxf(sqrtf(sp), 1e-12f);
  const float nn = fmaxf(sqrtf(sn), 1e-12f);

  float pos = 0.f, ng = 0.f;
  {
    float av, pv, nv, dp, dn;
    av = xa.x / na; pv = xp.x / np; nv = xn.x / nn;
    dp = av - pv + EPSF; pos += dp * dp; dn = av - nv + EPSF; ng += dn * dn;
    av = xa.y / na; pv = xp.y / np; nv = xn.y / nn;
    dp = av - pv + EPSF; pos += dp * dp; dn = av - nv + EPSF; ng += dn * dn;
    av = xa.z / na; pv = xp.z / np; nv = xn.z / nn;
    dp = av - pv + EPSF; pos += dp * dp; dn = av - nv + EPSF; ng += dn * dn;
    av = xa.w / na; pv = xp.w / np; nv = xn.w / nn;
    dp = av - pv + EPSF; pos += dp * dp; dn = av - nv + EPSF; ng += dn * dn;
  }
#pragma unroll
  for (int off = 32; off; off >>= 1) {
    pos += __shfl_xor(pos, off); ng += __shfl_xor(ng, off);
  }
  if (l == 0) rowloss[i] = fmaxf(pos - ng, 0.0f);
}

// ---------------- deterministic mean ----------------
__global__ __launch_bounds__(256) void finalize_kernel(
    const float* __restrict__ rowloss, float* __restrict__ out) {
  __shared__ float s[256];
  const int t = threadIdx.x;
  float a = 0.f;
  for (int k = 0; k < NB / 256; ++k) a += rowloss[t + 256 * k];
  s[t] = a;
  __syncthreads();
  for (int h = 128; h; h >>= 1) {
    if (t < h) s[t] += s[t + h];
    __syncthreads();
  }
  if (t == 0) out[0] = s[0] / (float)NB;
}

extern "C" void kernel_launch(void* const* d_in, const int* in_sizes, int n_in,
                              void* d_out, int out_size, void* d_ws, size_t ws_size,
                              hipStream_t stream) {
  (void)in_sizes; (void)n_in; (void)out_size; (void)ws_size;
  const float* x = (const float*)d_in[0];
  float* out = (float*)d_out;
  char* ws = (char*)d_ws;

  __hip_bfloat16* abf = (__hip_bfloat16*)(ws);                            // 4 MB
  __hip_bfloat16* pbf = (__hip_bfloat16*)(ws + (size_t)4 * 1024 * 1024);  // 4 MB
  Cand* part = (Cand*)(ws + (size_t)8 * 1024 * 1024);                     // 5.24 MB
  float* rowloss = (float*)(ws + (size_t)8 * 1024 * 1024 +
                            (size_t)NB * NSPLIT * 5 * sizeof(Cand));      // 32 KB

  // JAX: kr = key(1); k1, k2 = split(kr)  (threefry partitionable)
  U2 c0 = tf2x32(0u, 1u, 0u, 0u);
  U2 c1 = tf2x32(0u, 1u, 0u, 1u);
  const uint32_t k1a = c0.x, k1b = c0.y;
  const uint32_t k2a = c1.x, k2b = c1.y;

  prep_kernel<<<NB, 256, 0, stream>>>(x, abf, pbf);
  dist_topk_kernel<<<dim3(NB / 128, NSPLIT), 256, 0, stream>>>(abf, pbf, part);
  merge_loss_kernel<<<NB, 64, 0, stream>>>(x, part, rowloss, k1a, k1b, k2a, k2b);
  finalize_kernel<<<1, 256, 0, stream>>>(rowloss, out);
}

// Round 3
// 94.764 us; speedup vs baseline: 1.7435x; 1.3271x over previous
//
#include <hip/hip_runtime.h>
#include <hip/hip_bf16.h>
#include <stdint.h>

// B=8192 triplet loss with hard-negative mining.
// prep: normalize -> bf16 (vectorized, wave-local reductions only)
// dist_topk: barrier-free; B-fragments direct from global (L2), 64 rows/wave,
//            per-lane top-5 as packed u32 keys (value|inv-idx) via min/max CAS
// merge_loss: merge 16 sorted runs (uniform early-out), JAX threefry RNG,
//             exact fp32 loss per row
// finalize: deterministic mean

#define NB 8192
#define NSPLIT 16
#define EPSF 1e-6f

typedef float f32x4 __attribute__((ext_vector_type(4)));
typedef short short8 __attribute__((ext_vector_type(8)));

struct U2 { uint32_t x, y; };

__host__ __device__ __forceinline__ uint32_t rotl32(uint32_t v, int n) {
  return (v << n) | (v >> (32 - n));
}

__host__ __device__ __forceinline__ U2 tf2x32(uint32_t k0, uint32_t k1,
                                              uint32_t x0, uint32_t x1) {
  uint32_t k2 = k0 ^ k1 ^ 0x1BD11BDAu;
#define TF_R(r) { x0 += x1; x1 = rotl32(x1, r); x1 ^= x0; }
  x0 += k0; x1 += k1;
  TF_R(13) TF_R(15) TF_R(26) TF_R(6)
  x0 += k1; x1 += k2 + 1u;
  TF_R(17) TF_R(29) TF_R(16) TF_R(24)
  x0 += k2; x1 += k0 + 2u;
  TF_R(13) TF_R(15) TF_R(26) TF_R(6)
  x0 += k0; x1 += k1 + 3u;
  TF_R(17) TF_R(29) TF_R(16) TF_R(24)
  x0 += k1; x1 += k2 + 4u;
  TF_R(13) TF_R(15) TF_R(26) TF_R(6)
  x0 += k2; x1 += k0 + 5u;
#undef TF_R
  U2 r; r.x = x0; r.y = x1; return r;
}

__device__ __forceinline__ uint32_t rng_word(U2 r) { return r.x ^ r.y; }

// compare-and-swap: A = max, B = min (u32)
#define CAS2(A, B) { uint32_t _mx = (A) > (B) ? (A) : (B); \
                     uint32_t _mn = (A) > (B) ? (B) : (A); (A) = _mx; (B) = _mn; }
// bubble-insert candidate C into sorted-desc T0..T4 (C is clobbered)
#define INS5(T0, T1, T2, T3, T4, C) { CAS2(T4, C); CAS2(T3, T4); CAS2(T2, T3); \
                                      CAS2(T1, T2); CAS2(T0, T1); }

// ---------------- prep: normalize -> bf16 ----------------
__global__ __launch_bounds__(256) void prep_kernel(
    const float* __restrict__ x,
    __hip_bfloat16* __restrict__ abf, __hip_bfloat16* __restrict__ pbf) {
  const int w = threadIdx.x >> 6, l = threadIdx.x & 63;
  const int row = blockIdx.x * 4 + w;
  const float4* xr = (const float4*)(x + (size_t)row * 512);
  const float4 a4 = xr[l];
  const float4 p4 = xr[64 + l];
  float sa = a4.x * a4.x + a4.y * a4.y + a4.z * a4.z + a4.w * a4.w;
  float sp = p4.x * p4.x + p4.y * p4.y + p4.z * p4.z + p4.w * p4.w;
#pragma unroll
  for (int off = 32; off; off >>= 1) { sa += __shfl_xor(sa, off); sp += __shfl_xor(sp, off); }
  const float ia = 1.0f / fmaxf(sqrtf(sa), 1e-12f);
  const float ip_ = 1.0f / fmaxf(sqrtf(sp), 1e-12f);
  ushort4 ua, up;
  ua.x = __builtin_bit_cast(unsigned short, __float2bfloat16(a4.x * ia));
  ua.y = __builtin_bit_cast(unsigned short, __float2bfloat16(a4.y * ia));
  ua.z = __builtin_bit_cast(unsigned short, __float2bfloat16(a4.z * ia));
  ua.w = __builtin_bit_cast(unsigned short, __float2bfloat16(a4.w * ia));
  up.x = __builtin_bit_cast(unsigned short, __float2bfloat16(p4.x * ip_));
  up.y = __builtin_bit_cast(unsigned short, __float2bfloat16(p4.y * ip_));
  up.z = __builtin_bit_cast(unsigned short, __float2bfloat16(p4.z * ip_));
  up.w = __builtin_bit_cast(unsigned short, __float2bfloat16(p4.w * ip_));
  *(ushort4*)((char*)abf + (size_t)row * 512 + l * 8) = ua;
  *(ushort4*)((char*)pbf + (size_t)row * 512 + l * 8) = up;
}

// ---------------- dist + per-row top-5 (barrier-free, B from L2) ----------------
// grid: 512 blocks (1D, XCD-rect swizzled) x 256 thr = 4 independent waves.
// Wave owns 64 a-rows x 512 p-cols. mfma(bF, aF): for acc[mi]:
//   a-row (C col) = wrow + mi*16 + (l&15);  p-col (C row) = c0g + (l>>4)*4 + reg
__global__ __launch_bounds__(256, 2) void dist_topk_kernel(
    const __hip_bfloat16* __restrict__ abf, const __hip_bfloat16* __restrict__ pbf,
    uint32_t* __restrict__ part) {
  __shared__ uint32_t mls[4][1280]; // per-wave end-merge scratch (20 KB)

  const int tid = threadIdx.x;
  const int w = tid >> 6, l = tid & 63;
  const int lo = l & 15, hi = l >> 4;
  // XCD rectangle swizzle: xcd = b%8 (hw round-robin); give each XCD an
  // 8x8 (row-block x split) rect: A 1MB + B 2MB fits 4MB L2.
  const int b = blockIdx.x;
  const int xcd = b & 7, jj = b >> 3;
  const int xb = (xcd & 3) * 8 + (jj & 7);   // row-block 0..31 (256 rows each)
  const int sp = (xcd >> 2) * 8 + (jj >> 3); // col-split 0..15 (512 cols each)
  const int wrow = xb * 256 + w * 64;
  const bool hasDiag = (sp == (xb >> 1));

  // A fragments: 64 rows x 256 k, 128 VGPR
  short8 aF[4][8];
#pragma unroll
  for (int mi = 0; mi < 4; ++mi)
#pragma unroll
    for (int kk = 0; kk < 8; ++kk)
      aF[mi][kk] = *(const short8*)((const char*)abf +
                     (size_t)(wrow + mi * 16 + lo) * 512 + kk * 64 + hi * 16);

  uint32_t T[4][5];
#pragma unroll
  for (int mi = 0; mi < 4; ++mi)
#pragma unroll
    for (int q = 0; q < 5; ++q) T[mi][q] = 0u;

  const uint32_t vb = 8191u - (uint32_t)(hi * 4); // per-lane inv-index base
  const int colbase = sp * 512;

  for (int g = 0; g < 32; ++g) {
    const int c0g = colbase + g * 16;
    short8 bF[8];
#pragma unroll
    for (int kk = 0; kk < 8; ++kk)
      bF[kk] = *(const short8*)((const char*)pbf +
                  (size_t)(c0g + lo) * 512 + kk * 64 + hi * 16);
    f32x4 acc[4];
#pragma unroll
    for (int mi = 0; mi < 4; ++mi) { f32x4 z = {0.f, 0.f, 0.f, 0.f}; acc[mi] = z; }
#pragma unroll
    for (int kk = 0; kk < 8; ++kk)
#pragma unroll
      for (int mi = 0; mi < 4; ++mi)
        acc[mi] = __builtin_amdgcn_mfma_f32_16x16x32_bf16(bF[kk], aF[mi][kk], acc[mi], 0, 0, 0);

    // mine: key = (bits(ip+2) & ~0x1FFF) + (8191 - ci); u32-max == (ip desc, ci asc)
#pragma unroll
    for (int r = 0; r < 4; ++r) {
      const uint32_t tr = vb - (uint32_t)(c0g + r); // = 8191 - (c0g + hi*4 + r)
#pragma unroll
      for (int mi = 0; mi < 4; ++mi) {
        uint32_t key = (__float_as_uint(acc[mi][r] + 2.0f) & 0xFFFFE000u) + tr;
        if (hasDiag) {
          const int ci = c0g + hi * 4 + r;
          if (ci == wrow + mi * 16 + lo) key = 0u;
        }
        uint32_t c = key;
        INS5(T[mi][0], T[mi][1], T[mi][2], T[mi][3], T[mi][4], c);
      }
    }
  }

  // end-merge across the 4 hi-lanes of each row (one-shot)
#pragma unroll
  for (int mi = 0; mi < 4; ++mi)
#pragma unroll
    for (int q = 0; q < 5; ++q)
      mls[w][(mi * 16 + lo) * 20 + hi * 5 + q] = T[mi][q];
  __syncthreads();
  {
    uint32_t M0 = 0, M1 = 0, M2 = 0, M3 = 0, M4 = 0;
#pragma unroll
    for (int q = 0; q < 20; ++q) {
      uint32_t c = mls[w][l * 20 + q];
      INS5(M0, M1, M2, M3, M4, c);
    }
    const int row = wrow + l;
    uint32_t* dst = part + ((size_t)row * NSPLIT + sp) * 5;
    dst[0] = M0; dst[1] = M1; dst[2] = M2; dst[3] = M3; dst[4] = M4;
  }
}

// ---------------- merge splits + RNG + exact fp32 loss ----------------
__global__ __launch_bounds__(64) void merge_loss_kernel(
    const float* __restrict__ x, const uint32_t* __restrict__ part,
    float* __restrict__ rowloss,
    uint32_t k1a, uint32_t k1b, uint32_t k2a, uint32_t k2b) {
  const int i = blockIdx.x, l = threadIdx.x;
  __shared__ uint32_t cs[80];
  const uint32_t* src = part + (size_t)i * (NSPLIT * 5);
  cs[l] = src[l];
  if (l < 16) cs[64 + l] = src[64 + l];
  __syncthreads();

  uint32_t T0 = 0, T1 = 0, T2 = 0, T3 = 0, T4 = 0;
  for (int rch = 0; rch < 16; ++rch) {
    for (int q = 0; q < 5; ++q) {      // runs are sorted desc -> early out (uniform)
      uint32_t c = cs[rch * 5 + q];
      if (c <= T4) break;
      INS5(T0, T1, T2, T3, T4, c);
    }
  }

  // RNG: coin = uniform(k1) < 0.5 <=> MSB==0 ; randint(k2,0,5)
  const uint32_t cw = rng_word(tf2x32(k1a, k1b, 0u, (uint32_t)i));
  const bool coin = (cw >> 31) == 0u;
  const uint32_t hb = rng_word(tf2x32(k2a, k2b, 0u, (uint32_t)i));
  const uint32_t lb = rng_word(tf2x32(k2a, k2b, 0u, (uint32_t)(NB + i)));
  const int rr = (int)(((hb % 5u) + (lb % 5u)) % 5u);
  const int rank = coin ? 0 : rr;
  const uint32_t kch = (rank == 0) ? T0 : (rank == 1) ? T1 : (rank == 2) ? T2
                     : (rank == 3) ? T3 : T4;
  const int neg = 8191 - (int)(kch & 8191u);

  // exact fp32 loss from raw x
  const float4 xa = *(const float4*)(x + (size_t)i * 512 + l * 4);
  const float4 xp = *(const float4*)(x + (size_t)i * 512 + 256 + l * 4);
  const float4 xn = *(const float4*)(x + (size_t)neg * 512 + 256 + l * 4);
  float sa = xa.x * xa.x + xa.y * xa.y + xa.z * xa.z + xa.w * xa.w;
  float sp = xp.x * xp.x + xp.y * xp.y + xp.z * xp.z + xp.w * xp.w;
  float sn = xn.x * xn.x + xn.y * xn.y + xn.z * xn.z + xn.w * xn.w;
#pragma unroll
  for (int off = 32; off; off >>= 1) {
    sa += __shfl_xor(sa, off); sp += __shfl_xor(sp, off); sn += __shfl_xor(sn, off);
  }
  const float na = fmaxf(sqrtf(sa), 1e-12f);
  const float np = fmaxf(sqrtf(sp), 1e-12f);
  const float nn = fmaxf(sqrtf(sn), 1e-12f);

  float pos = 0.f, ng = 0.f;
  {
    float av, pv, nv, dp, dn;
    av = xa.x / na; pv = xp.x / np; nv = xn.x / nn;
    dp = av - pv + EPSF; pos += dp * dp; dn = av - nv + EPSF; ng += dn * dn;
    av = xa.y / na; pv = xp.y / np; nv = xn.y / nn;
    dp = av - pv + EPSF; pos += dp * dp; dn = av - nv + EPSF; ng += dn * dn;
    av = xa.z / na; pv = xp.z / np; nv = xn.z / nn;
    dp = av - pv + EPSF; pos += dp * dp; dn = av - nv + EPSF; ng += dn * dn;
    av = xa.w / na; pv = xp.w / np; nv = xn.w / nn;
    dp = av - pv + EPSF; pos += dp * dp; dn = av - nv + EPSF; ng += dn * dn;
  }
#pragma unroll
  for (int off = 32; off; off >>= 1) {
    pos += __shfl_xor(pos, off); ng += __shfl_xor(ng, off);
  }
  if (l == 0) rowloss[i] = fmaxf(pos - ng, 0.0f);
}

// ---------------- deterministic mean ----------------
__global__ __launch_bounds__(256) void finalize_kernel(
    const float* __restrict__ rowloss, float* __restrict__ out) {
  __shared__ float s[256];
  const int t = threadIdx.x;
  float a = 0.f;
  for (int k = 0; k < NB / 256; ++k) a += rowloss[t + 256 * k];
  s[t] = a;
  __syncthreads();
  for (int h = 128; h; h >>= 1) {
    if (t < h) s[t] += s[t + h];
    __syncthreads();
  }
  if (t == 0) out[0] = s[0] / (float)NB;
}

extern "C" void kernel_launch(void* const* d_in, const int* in_sizes, int n_in,
                              void* d_out, int out_size, void* d_ws, size_t ws_size,
                              hipStream_t stream) {
  (void)in_sizes; (void)n_in; (void)out_size; (void)ws_size;
  const float* x = (const float*)d_in[0];
  float* out = (float*)d_out;
  char* ws = (char*)d_ws;

  __hip_bfloat16* abf = (__hip_bfloat16*)(ws);                            // 4 MB
  __hip_bfloat16* pbf = (__hip_bfloat16*)(ws + (size_t)4 * 1024 * 1024);  // 4 MB
  uint32_t* part = (uint32_t*)(ws + (size_t)8 * 1024 * 1024);             // 2.62 MB
  float* rowloss = (float*)(ws + (size_t)8 * 1024 * 1024 +
                            (size_t)NB * NSPLIT * 5 * sizeof(uint32_t));  // 32 KB

  // JAX: kr = key(1); k1, k2 = split(kr)  (threefry partitionable)
  U2 c0 = tf2x32(0u, 1u, 0u, 0u);
  U2 c1 = tf2x32(0u, 1u, 0u, 1u);
  const uint32_t k1a = c0.x, k1b = c0.y;
  const uint32_t k2a = c1.x, k2b = c1.y;

  prep_kernel<<<NB / 4, 256, 0, stream>>>(x, abf, pbf);
  dist_topk_kernel<<<512, 256, 0, stream>>>(abf, pbf, part);
  merge_loss_kernel<<<NB, 64, 0, stream>>>(x, part, rowloss, k1a, k1b, k2a, k2b);
  finalize_kernel<<<1, 256, 0, stream>>>(rowloss, out);
}